// Round 3
// baseline (732.627 us; speedup 1.0000x reference)
//
#include <hip/hip_runtime.h>
#include <hip/hip_bf16.h>

// GCN 2-layer: out = Ahat * relu(Ahat*(X W1)+b1) * W2 + b2
// Round 3: bucketed two-pass counting sort for CSR build (kills the 105MB
// write-amplified random scatter of fill_csr + the deg_count random atomics).
//   pass 1: bucket edges by dst>>6 (appends are line-dense, L2-resident)
//   pass 2: per-bucket LDS histogram -> cnt+dinv coalesced; scan; per-bucket
//           LDS-cursor scatter into the final CSR (dense 4KB windows)
// GEMMs (dinv folded into epilogue) and pull-aggregation unchanged.

#define N_FEAT_IN 64
#define BSHIFT 6   // 64 dst nodes per bucket

// ---- pass 1a: bucket histogram ----
__global__ __launch_bounds__(256) void bucket_hist(const int* __restrict__ dst,
                                                   int* __restrict__ bhist, int E) {
    int e = blockIdx.x * 256 + threadIdx.x;
    if (e < E) atomicAdd(&bhist[dst[e] >> BSHIFT], 1);
}

// ---- pass 1b: exclusive scan over NB (<=2048) buckets, single block ----
__global__ __launch_bounds__(1024) void bucket_scan(const int* __restrict__ bhist,
                                                    int* __restrict__ bbase,
                                                    int* __restrict__ bcursor,
                                                    int NB, int E) {
    __shared__ int s[2048];
    int t = threadIdx.x;
    int v0 = (t < NB) ? bhist[t] : 0;
    int v1 = (t + 1024 < NB) ? bhist[t + 1024] : 0;
    s[t] = v0;
    s[t + 1024] = v1;
    __syncthreads();
    for (int off = 1; off < 2048; off <<= 1) {
        int a = (t >= off) ? s[t - off] : 0;
        int b = (t + 1024 >= off) ? s[t + 1024 - off] : 0;
        __syncthreads();
        s[t] += a;
        s[t + 1024] += b;
        __syncthreads();
    }
    int e0 = s[t] - v0, e1 = s[t + 1024] - v1;
    if (t < NB) { bbase[t] = e0; bcursor[t] = e0; }
    if (t + 1024 < NB) { bbase[t + 1024] = e1; bcursor[t + 1024] = e1; }
    if (t == 0) bbase[NB] = E;
}

// ---- pass 1c: append packed (src<<6 | dst&63) into bucket regions ----
__global__ __launch_bounds__(256) void bucket_fill(const int* __restrict__ src,
                                                   const int* __restrict__ dst,
                                                   int* __restrict__ bcursor,
                                                   unsigned* __restrict__ bedges, int E) {
    int e = blockIdx.x * 256 + threadIdx.x;
    if (e < E) {
        int d = dst[e];
        int pos = atomicAdd(&bcursor[d >> BSHIFT], 1);
        bedges[pos] = ((unsigned)src[e] << BSHIFT) | (unsigned)(d & 63);
    }
}

// ---- pass 2a: per-bucket histogram -> cnt[d] (coalesced) + dinv[d] ----
__global__ __launch_bounds__(256) void bucket_cnt(const int* __restrict__ bbase,
                                                  const unsigned* __restrict__ bedges,
                                                  int* __restrict__ cnt,
                                                  float* __restrict__ dinv, int n) {
    int b = blockIdx.x;
    __shared__ int lh[64];
    if (threadIdx.x < 64) lh[threadIdx.x] = 0;
    __syncthreads();
    int beg = bbase[b], end = bbase[b + 1];
    for (int i = beg + threadIdx.x; i < end; i += 256)
        atomicAdd(&lh[bedges[i] & 63], 1);
    __syncthreads();
    if (threadIdx.x < 64) {
        int d = (b << BSHIFT) + threadIdx.x;
        if (d < n) {
            int c = lh[threadIdx.x];
            cnt[d] = c;
            dinv[d] = rsqrtf((float)c + 1.0f);
        }
    }
}

// ---- 3-phase exclusive scan over cnt[n] -> row_ptr[n+1] ----
__global__ __launch_bounds__(256) void scan_phase1(const int* __restrict__ cnt,
                                                   int* __restrict__ excl,
                                                   int* __restrict__ bsum, int n) {
    __shared__ int s[256];
    int t = threadIdx.x;
    int i = blockIdx.x * 256 + t;
    int v = (i < n) ? cnt[i] : 0;
    s[t] = v;
    __syncthreads();
    for (int off = 1; off < 256; off <<= 1) {
        int add = (t >= off) ? s[t - off] : 0;
        __syncthreads();
        s[t] += add;
        __syncthreads();
    }
    if (i < n) excl[i] = s[t] - v;
    if (t == 255) bsum[blockIdx.x] = s[255];
}

__global__ __launch_bounds__(512) void scan_phase2(int* __restrict__ bsum, int nb) {
    __shared__ int s[512];
    int t = threadIdx.x;
    int v = (t < nb) ? bsum[t] : 0;
    s[t] = v;
    __syncthreads();
    for (int off = 1; off < 512; off <<= 1) {
        int add = (t >= off) ? s[t - off] : 0;
        __syncthreads();
        s[t] += add;
        __syncthreads();
    }
    if (t < nb) bsum[t] = s[t] - v;
}

__global__ __launch_bounds__(256) void scan_phase3(int* __restrict__ row_ptr,
                                                   const int* __restrict__ bsum,
                                                   int n, int E) {
    int i = blockIdx.x * 256 + threadIdx.x;
    if (i < n) row_ptr[i] += bsum[blockIdx.x];
    if (i == 0) row_ptr[n] = E;
}

// ---- pass 2b: scatter src into CSR via LDS cursors (dense windows) ----
__global__ __launch_bounds__(256) void csr_fill(const int* __restrict__ bbase,
                                                const unsigned* __restrict__ bedges,
                                                const int* __restrict__ row_ptr,
                                                int* __restrict__ csr_src, int n) {
    int b = blockIdx.x;
    __shared__ int cur[64];
    if (threadIdx.x < 64) {
        int d = (b << BSHIFT) + threadIdx.x;
        cur[threadIdx.x] = (d < n) ? row_ptr[d] : 0;
    }
    __syncthreads();
    int beg = bbase[b], end = bbase[b + 1];
    for (int i = beg + threadIdx.x; i < end; i += 256) {
        unsigned v = bedges[i];
        int pos = atomicAdd(&cur[v & 63], 1);
        csr_src[pos] = (int)(v >> BSHIFT);
    }
}

// ---- GEMM: out[n,FO] = dinv[row] * (preop(A[n,64]) * W[64,FO]) ----
template <int FO, bool RELU_BIAS>
__global__ __launch_bounds__(256) void gemm_rows(const float* __restrict__ A,
                                                 const float* __restrict__ W,
                                                 const float* __restrict__ bias,
                                                 const float* __restrict__ dinv,
                                                 float* __restrict__ out, int n) {
    constexpr int K = 64;
    constexpr int CPT = FO / 4;
    __shared__ float As[64][K + 4];
    __shared__ float Ws[K][FO];

    const int t = threadIdx.x;
    const int r0 = blockIdx.x * 64;

    constexpr int W4 = K * FO / 4;
    for (int i = t; i < W4; i += 256) {
        int k = i / (FO / 4);
        int c4 = (i % (FO / 4)) * 4;
        *(float4*)&Ws[k][c4] = *(const float4*)&W[k * FO + c4];
    }
    for (int i = t; i < 1024; i += 256) {
        int row = i / 16;
        int c4 = (i % 16) * 4;
        int g = r0 + row;
        float4 v = make_float4(0.f, 0.f, 0.f, 0.f);
        if (g < n) {
            v = *(const float4*)&A[(size_t)g * K + c4];
            if (RELU_BIAS) {
                v.x = fmaxf(v.x + bias[c4 + 0], 0.f);
                v.y = fmaxf(v.y + bias[c4 + 1], 0.f);
                v.z = fmaxf(v.z + bias[c4 + 2], 0.f);
                v.w = fmaxf(v.w + bias[c4 + 3], 0.f);
            }
        }
        *(float4*)&As[row][c4] = v;
    }
    __syncthreads();

    const int row = t >> 2;
    const int c0 = (t & 3) * CPT;
    float acc[CPT];
#pragma unroll
    for (int j = 0; j < CPT; ++j) acc[j] = 0.f;

#pragma unroll
    for (int k = 0; k < K; ++k) {
        float xv = As[row][k];
#pragma unroll
        for (int j = 0; j < CPT; ++j) acc[j] = fmaf(xv, Ws[k][c0 + j], acc[j]);
    }

    int g = r0 + row;
    if (g < n) {
        float sc = dinv[g];
#pragma unroll
        for (int j4 = 0; j4 < CPT; j4 += 4) {
            float4 v = make_float4(acc[j4] * sc, acc[j4 + 1] * sc,
                                   acc[j4 + 2] * sc, acc[j4 + 3] * sc);
            *(float4*)&out[(size_t)g * FO + c0 + j4] = v;
        }
    }
}

// ---- pull aggregation: out[d,f] = dinv[d]*(sum_{s in N(d)} xs[s,f] + xs[d,f]) (+bias) ----
template <int F, bool ADD_BIAS>
__global__ __launch_bounds__(256) void aggregate(const int* __restrict__ row_ptr,
                                                 const int* __restrict__ csr_src,
                                                 const float* __restrict__ dinv,
                                                 const float* __restrict__ xs,
                                                 const float* __restrict__ bias,
                                                 float* __restrict__ out, int n) {
    constexpr int NPB = 256 / F;
    constexpr int SH = (F == 64) ? 6 : 5;
    int d = blockIdx.x * NPB + (threadIdx.x >> SH);
    int f = threadIdx.x & (F - 1);
    if (d >= n) return;

    int beg = row_ptr[d];
    int end = row_ptr[d + 1];
    float acc = xs[(size_t)d * F + f];
    int j = beg;
    for (; j + 4 <= end; j += 4) {
        int s0 = csr_src[j + 0];
        int s1 = csr_src[j + 1];
        int s2 = csr_src[j + 2];
        int s3 = csr_src[j + 3];
        float v0 = xs[(size_t)s0 * F + f];
        float v1 = xs[(size_t)s1 * F + f];
        float v2 = xs[(size_t)s2 * F + f];
        float v3 = xs[(size_t)s3 * F + f];
        acc += (v0 + v1) + (v2 + v3);
    }
    for (; j < end; ++j) acc += xs[(size_t)csr_src[j] * F + f];

    float r = dinv[d] * acc;
    if (ADD_BIAS) r += bias[f];
    out[(size_t)d * F + f] = r;
}

extern "C" void kernel_launch(void* const* d_in, const int* in_sizes, int n_in,
                              void* d_out, int out_size, void* d_ws, size_t ws_size,
                              hipStream_t stream) {
    const float* x  = (const float*)d_in[0];   // [n, 64]
    const int*   ei = (const int*)d_in[1];     // [2, E]
    const float* W1 = (const float*)d_in[2];   // [64, 64]
    const float* b1 = (const float*)d_in[3];   // [64]
    const float* W2 = (const float*)d_in[4];   // [64, 32]
    const float* b2 = (const float*)d_in[5];   // [32]
    float* out = (float*)d_out;                // [n, 32]

    const int n = in_sizes[0] / N_FEAT_IN;     // 100000
    const int E = in_sizes[1] / 2;             // 1600000
    const int* srcI = ei;
    const int* dstI = ei + E;

    const int NB   = (n + 63) >> BSHIFT;       // 1563 buckets (<=2048)
    const int NBLK = (n + 255) / 256;          // scan blocks (391)

    // workspace layout (256B aligned)
    char* ws = (char*)d_ws;
    size_t off = 0;
    auto alloc = [&](size_t bytes) {
        void* p = ws + off;
        off += (bytes + 255) & ~(size_t)255;
        return p;
    };
    int*      cnt     = (int*)alloc((size_t)n * 4);
    float*    dinv    = (float*)alloc((size_t)n * 4);
    int*      row_ptr = (int*)alloc((size_t)(n + 1) * 4);
    int*      bsum    = (int*)alloc((size_t)512 * 4);
    int*      bhist   = (int*)alloc((size_t)2048 * 4);
    int*      bbase   = (int*)alloc((size_t)2049 * 4);
    int*      bcursor = (int*)alloc((size_t)2048 * 4);
    unsigned* bedges  = (unsigned*)alloc((size_t)E * 4);
    int*      csr_src = (int*)alloc((size_t)E * 4);
    float*    xs      = (float*)alloc((size_t)n * 64 * 4);
    float*    agg1    = (float*)alloc((size_t)n * 64 * 4);

    // 1) bucket sort by dst -> bedges grouped by dst>>6
    hipMemsetAsync(bhist, 0, (size_t)NB * sizeof(int), stream);
    bucket_hist<<<(E + 255) / 256, 256, 0, stream>>>(dstI, bhist, E);
    bucket_scan<<<1, 1024, 0, stream>>>(bhist, bbase, bcursor, NB, E);
    bucket_fill<<<(E + 255) / 256, 256, 0, stream>>>(srcI, dstI, bcursor, bedges, E);

    // 2) per-node counts + dinv (coalesced), row_ptr scan, CSR scatter
    bucket_cnt<<<NB, 256, 0, stream>>>(bbase, bedges, cnt, dinv, n);
    scan_phase1<<<NBLK, 256, 0, stream>>>(cnt, row_ptr, bsum, n);
    scan_phase2<<<1, 512, 0, stream>>>(bsum, NBLK);
    scan_phase3<<<NBLK, 256, 0, stream>>>(row_ptr, bsum, n, E);
    csr_fill<<<NB, 256, 0, stream>>>(bbase, bedges, row_ptr, csr_src, n);

    // 3) layer 1: xs = dinv .* (X W1); agg1 = dinv .* (gather-sum + self)
    gemm_rows<64, false><<<(n + 63) / 64, 256, 0, stream>>>(x, W1, nullptr, dinv, xs, n);
    aggregate<64, false><<<(n + 3) / 4, 256, 0, stream>>>(row_ptr, csr_src, dinv, xs, nullptr, agg1, n);

    // 4) layer 2: xs2 = dinv .* (relu(agg1+b1) W2); out = dinv .* (gather-sum + self) + b2
    gemm_rows<32, true><<<(n + 63) / 64, 256, 0, stream>>>(agg1, W2, b1, dinv, xs, n);
    aggregate<32, true><<<(n + 7) / 8, 256, 0, stream>>>(row_ptr, csr_src, dinv, xs, b2, out, n);
}

// Round 4
// 379.332 us; speedup vs baseline: 1.9314x; 1.9314x over previous
//
#include <hip/hip_runtime.h>
#include <hip/hip_bf16.h>

// GCN 2-layer: out = Ahat * relu(Ahat*(X W1)+b1) * W2 + b2
// Round 4: ATOMIC-FREE CSR build via block-histogram matrix.
//   passA: per-chunk LDS hist over 196 coarse buckets (dst>>9) -> H[chunk][256]
//   col_scan: column scan of H -> per-(chunk,bucket) exclusive global bases
//   passB: re-read chunk, place packed (src<<9|dst&511) via LDS cursors into
//          private per-chunk runs (no global atomics, writes clustered)
//   then per-bucket LDS hist -> cnt+dinv, row_ptr scan, LDS-cursor csr_fill.
// GEMMs (dinv folded) and pull-aggregation unchanged from round 2.

#define N_FEAT_IN 64
#define B2SHIFT 9        // 512 dst nodes per coarse bucket
#define CHUNK 4096       // edges per block in pass A/B

// ---- pass A: per-chunk bucket histogram (LDS, no global atomics) ----
__global__ __launch_bounds__(256) void passA_hist(const int* __restrict__ dst,
                                                  int* __restrict__ H, int E) {
    __shared__ int h[256];
    h[threadIdx.x] = 0;
    __syncthreads();
    int base = blockIdx.x * CHUNK;
    int end = min(base + CHUNK, E);
    for (int i = base + threadIdx.x; i < end; i += 256)
        atomicAdd(&h[dst[i] >> B2SHIFT], 1);
    __syncthreads();
    H[blockIdx.x * 256 + threadIdx.x] = h[threadIdx.x];
}

// ---- column scan of H: H[r][b] becomes exclusive base; bbase[b] per bucket ----
__global__ __launch_bounds__(256) void col_scan(int* __restrict__ H,
                                                int* __restrict__ bbase,
                                                int NR, int NB, int E) {
    int t = threadIdx.x;
    int tot = 0;
    for (int r = 0; r < NR; ++r) tot += H[r * 256 + t];  // coalesced rows
    __shared__ int s[256];
    s[t] = tot;
    __syncthreads();
    for (int off = 1; off < 256; off <<= 1) {
        int a = (t >= off) ? s[t - off] : 0;
        __syncthreads();
        s[t] += a;
        __syncthreads();
    }
    int bb = s[t] - tot;  // exclusive bucket base
    if (t < NB) bbase[t] = bb;
    if (t == 0) bbase[NB] = E;
    int run = bb;
    for (int r = 0; r < NR; ++r) {
        int v = H[r * 256 + t];
        H[r * 256 + t] = run;
        run += v;
    }
}

// ---- pass B: place packed edges into private per-chunk runs ----
__global__ __launch_bounds__(256) void passB_place(const int* __restrict__ src,
                                                   const int* __restrict__ dst,
                                                   const int* __restrict__ H,
                                                   unsigned* __restrict__ bedges, int E) {
    __shared__ int cur[256];
    cur[threadIdx.x] = H[blockIdx.x * 256 + threadIdx.x];
    __syncthreads();
    int base = blockIdx.x * CHUNK;
    int end = min(base + CHUNK, E);
    for (int i = base + threadIdx.x; i < end; i += 256) {
        int d = dst[i];
        int p = atomicAdd(&cur[d >> B2SHIFT], 1);  // LDS atomic
        bedges[p] = ((unsigned)src[i] << B2SHIFT) | (unsigned)(d & 511);
    }
}

// ---- per-bucket histogram -> cnt[d] + dinv[d] (coalesced writes) ----
__global__ __launch_bounds__(256) void bucket_cnt(const int* __restrict__ bbase,
                                                  const unsigned* __restrict__ bedges,
                                                  int* __restrict__ cnt,
                                                  float* __restrict__ dinv, int n) {
    __shared__ int lh[512];
    lh[threadIdx.x] = 0;
    lh[threadIdx.x + 256] = 0;
    __syncthreads();
    int b = blockIdx.x;
    int beg = bbase[b], end = bbase[b + 1];
    for (int i = beg + threadIdx.x; i < end; i += 256)
        atomicAdd(&lh[bedges[i] & 511], 1);
    __syncthreads();
#pragma unroll
    for (int k = 0; k < 2; ++k) {
        int d = (b << B2SHIFT) + threadIdx.x + k * 256;
        if (d < n) {
            int c = lh[threadIdx.x + k * 256];
            cnt[d] = c;
            dinv[d] = rsqrtf((float)c + 1.0f);
        }
    }
}

// ---- 3-phase exclusive scan over cnt[n] -> row_ptr[n+1] ----
__global__ __launch_bounds__(256) void scan_phase1(const int* __restrict__ cnt,
                                                   int* __restrict__ excl,
                                                   int* __restrict__ bsum, int n) {
    __shared__ int s[256];
    int t = threadIdx.x;
    int i = blockIdx.x * 256 + t;
    int v = (i < n) ? cnt[i] : 0;
    s[t] = v;
    __syncthreads();
    for (int off = 1; off < 256; off <<= 1) {
        int add = (t >= off) ? s[t - off] : 0;
        __syncthreads();
        s[t] += add;
        __syncthreads();
    }
    if (i < n) excl[i] = s[t] - v;
    if (t == 255) bsum[blockIdx.x] = s[255];
}

__global__ __launch_bounds__(512) void scan_phase2(int* __restrict__ bsum, int nb) {
    __shared__ int s[512];
    int t = threadIdx.x;
    int v = (t < nb) ? bsum[t] : 0;
    s[t] = v;
    __syncthreads();
    for (int off = 1; off < 512; off <<= 1) {
        int add = (t >= off) ? s[t - off] : 0;
        __syncthreads();
        s[t] += add;
        __syncthreads();
    }
    if (t < nb) bsum[t] = s[t] - v;
}

__global__ __launch_bounds__(256) void scan_phase3(int* __restrict__ row_ptr,
                                                   const int* __restrict__ bsum,
                                                   int n, int E) {
    int i = blockIdx.x * 256 + threadIdx.x;
    if (i < n) row_ptr[i] += bsum[blockIdx.x];
    if (i == 0) row_ptr[n] = E;
}

// ---- scatter src into CSR via 512 LDS cursors (dense 32KB windows) ----
__global__ __launch_bounds__(256) void csr_fill(const int* __restrict__ bbase,
                                                const unsigned* __restrict__ bedges,
                                                const int* __restrict__ row_ptr,
                                                int* __restrict__ csr_src, int n) {
    __shared__ int cur[512];
#pragma unroll
    for (int k = 0; k < 2; ++k) {
        int d = (blockIdx.x << B2SHIFT) + threadIdx.x + k * 256;
        cur[threadIdx.x + k * 256] = (d < n) ? row_ptr[d] : 0;
    }
    __syncthreads();
    int beg = bbase[blockIdx.x], end = bbase[blockIdx.x + 1];
    for (int i = beg + threadIdx.x; i < end; i += 256) {
        unsigned v = bedges[i];
        int p = atomicAdd(&cur[v & 511], 1);  // LDS atomic
        csr_src[p] = (int)(v >> B2SHIFT);
    }
}

// ---- GEMM: out[n,FO] = dinv[row] * (preop(A[n,64]) * W[64,FO]) ----
template <int FO, bool RELU_BIAS>
__global__ __launch_bounds__(256) void gemm_rows(const float* __restrict__ A,
                                                 const float* __restrict__ W,
                                                 const float* __restrict__ bias,
                                                 const float* __restrict__ dinv,
                                                 float* __restrict__ out, int n) {
    constexpr int K = 64;
    constexpr int CPT = FO / 4;
    __shared__ float As[64][K + 4];
    __shared__ float Ws[K][FO];

    const int t = threadIdx.x;
    const int r0 = blockIdx.x * 64;

    constexpr int W4 = K * FO / 4;
    for (int i = t; i < W4; i += 256) {
        int k = i / (FO / 4);
        int c4 = (i % (FO / 4)) * 4;
        *(float4*)&Ws[k][c4] = *(const float4*)&W[k * FO + c4];
    }
    for (int i = t; i < 1024; i += 256) {
        int row = i / 16;
        int c4 = (i % 16) * 4;
        int g = r0 + row;
        float4 v = make_float4(0.f, 0.f, 0.f, 0.f);
        if (g < n) {
            v = *(const float4*)&A[(size_t)g * K + c4];
            if (RELU_BIAS) {
                v.x = fmaxf(v.x + bias[c4 + 0], 0.f);
                v.y = fmaxf(v.y + bias[c4 + 1], 0.f);
                v.z = fmaxf(v.z + bias[c4 + 2], 0.f);
                v.w = fmaxf(v.w + bias[c4 + 3], 0.f);
            }
        }
        *(float4*)&As[row][c4] = v;
    }
    __syncthreads();

    const int row = t >> 2;
    const int c0 = (t & 3) * CPT;
    float acc[CPT];
#pragma unroll
    for (int j = 0; j < CPT; ++j) acc[j] = 0.f;

#pragma unroll
    for (int k = 0; k < K; ++k) {
        float xv = As[row][k];
#pragma unroll
        for (int j = 0; j < CPT; ++j) acc[j] = fmaf(xv, Ws[k][c0 + j], acc[j]);
    }

    int g = r0 + row;
    if (g < n) {
        float sc = dinv[g];
#pragma unroll
        for (int j4 = 0; j4 < CPT; j4 += 4) {
            float4 v = make_float4(acc[j4] * sc, acc[j4 + 1] * sc,
                                   acc[j4 + 2] * sc, acc[j4 + 3] * sc);
            *(float4*)&out[(size_t)g * FO + c0 + j4] = v;
        }
    }
}

// ---- pull aggregation: out[d,f] = dinv[d]*(sum_{s in N(d)} xs[s,f] + xs[d,f]) (+bias) ----
template <int F, bool ADD_BIAS>
__global__ __launch_bounds__(256) void aggregate(const int* __restrict__ row_ptr,
                                                 const int* __restrict__ csr_src,
                                                 const float* __restrict__ dinv,
                                                 const float* __restrict__ xs,
                                                 const float* __restrict__ bias,
                                                 float* __restrict__ out, int n) {
    constexpr int NPB = 256 / F;
    constexpr int SH = (F == 64) ? 6 : 5;
    int d = blockIdx.x * NPB + (threadIdx.x >> SH);
    int f = threadIdx.x & (F - 1);
    if (d >= n) return;

    int beg = row_ptr[d];
    int end = row_ptr[d + 1];
    float acc = xs[(size_t)d * F + f];
    int j = beg;
    for (; j + 4 <= end; j += 4) {
        int s0 = csr_src[j + 0];
        int s1 = csr_src[j + 1];
        int s2 = csr_src[j + 2];
        int s3 = csr_src[j + 3];
        float v0 = xs[(size_t)s0 * F + f];
        float v1 = xs[(size_t)s1 * F + f];
        float v2 = xs[(size_t)s2 * F + f];
        float v3 = xs[(size_t)s3 * F + f];
        acc += (v0 + v1) + (v2 + v3);
    }
    for (; j < end; ++j) acc += xs[(size_t)csr_src[j] * F + f];

    float r = dinv[d] * acc;
    if (ADD_BIAS) r += bias[f];
    out[(size_t)d * F + f] = r;
}

extern "C" void kernel_launch(void* const* d_in, const int* in_sizes, int n_in,
                              void* d_out, int out_size, void* d_ws, size_t ws_size,
                              hipStream_t stream) {
    const float* x  = (const float*)d_in[0];   // [n, 64]
    const int*   ei = (const int*)d_in[1];     // [2, E]
    const float* W1 = (const float*)d_in[2];   // [64, 64]
    const float* b1 = (const float*)d_in[3];   // [64]
    const float* W2 = (const float*)d_in[4];   // [64, 32]
    const float* b2 = (const float*)d_in[5];   // [32]
    float* out = (float*)d_out;                // [n, 32]

    const int n = in_sizes[0] / N_FEAT_IN;     // 100000
    const int E = in_sizes[1] / 2;             // 1600000
    const int* srcI = ei;
    const int* dstI = ei + E;

    const int NB     = (n + 511) >> B2SHIFT;   // 196 coarse buckets
    const int NR     = (E + CHUNK - 1) / CHUNK;// 391 chunks
    const int NBLK   = (n + 255) / 256;        // row_ptr scan blocks (391)

    // workspace layout (256B aligned)
    char* ws = (char*)d_ws;
    size_t off = 0;
    auto alloc = [&](size_t bytes) {
        void* p = ws + off;
        off += (bytes + 255) & ~(size_t)255;
        return p;
    };
    int*      cnt     = (int*)alloc((size_t)n * 4);
    float*    dinv    = (float*)alloc((size_t)n * 4);
    int*      row_ptr = (int*)alloc((size_t)(n + 1) * 4);
    int*      bsum    = (int*)alloc((size_t)512 * 4);
    int*      bbase   = (int*)alloc((size_t)(NB + 1) * 4);
    int*      H       = (int*)alloc((size_t)NR * 256 * 4);   // ~400KB
    unsigned* bedges  = (unsigned*)alloc((size_t)E * 4);
    int*      csr_src = (int*)alloc((size_t)E * 4);
    float*    xs      = (float*)alloc((size_t)n * 64 * 4);
    float*    agg1    = (float*)alloc((size_t)n * 64 * 4);

    // 1) atomic-free bucket sort by dst>>9
    passA_hist<<<NR, 256, 0, stream>>>(dstI, H, E);
    col_scan<<<1, 256, 0, stream>>>(H, bbase, NR, NB, E);
    passB_place<<<NR, 256, 0, stream>>>(srcI, dstI, H, bedges, E);

    // 2) per-node counts + dinv, row_ptr scan, CSR scatter
    bucket_cnt<<<NB, 256, 0, stream>>>(bbase, bedges, cnt, dinv, n);
    scan_phase1<<<NBLK, 256, 0, stream>>>(cnt, row_ptr, bsum, n);
    scan_phase2<<<1, 512, 0, stream>>>(bsum, NBLK);
    scan_phase3<<<NBLK, 256, 0, stream>>>(row_ptr, bsum, n, E);
    csr_fill<<<NB, 256, 0, stream>>>(bbase, bedges, row_ptr, csr_src, n);

    // 3) layer 1: xs = dinv .* (X W1); agg1 = dinv .* (gather-sum + self)
    gemm_rows<64, false><<<(n + 63) / 64, 256, 0, stream>>>(x, W1, nullptr, dinv, xs, n);
    aggregate<64, false><<<(n + 3) / 4, 256, 0, stream>>>(row_ptr, csr_src, dinv, xs, nullptr, agg1, n);

    // 4) layer 2: xs2 = dinv .* (relu(agg1+b1) W2); out = dinv .* (gather-sum + self) + b2
    gemm_rows<32, true><<<(n + 63) / 64, 256, 0, stream>>>(agg1, W2, b1, dinv, xs, n);
    aggregate<32, true><<<(n + 7) / 8, 256, 0, stream>>>(row_ptr, csr_src, dinv, xs, b2, out, n);
}

// Round 5
// 293.861 us; speedup vs baseline: 2.4931x; 1.2909x over previous
//
#include <hip/hip_runtime.h>
#include <hip/hip_bf16.h>

// GCN 2-layer: out = Ahat * relu(Ahat*(X W1)+b1) * W2 + b2
// Round 5: parallelize the H-matrix column scan (round 4's col_scan was a
// single-block serial kernel = 98us latency hole; now 3 parallel kernels).
// Rest identical to round 4: atomic-free bucketed CSR build, dinv folded
// into GEMM epilogue, CSR pull-aggregation.

#define N_FEAT_IN 64
#define B2SHIFT 9        // 512 dst nodes per coarse bucket
#define CHUNK 4096       // edges per block in pass A/B

// ---- pass A: per-chunk bucket histogram (LDS, no global atomics) ----
__global__ __launch_bounds__(256) void passA_hist(const int* __restrict__ dst,
                                                  int* __restrict__ H, int E) {
    __shared__ int h[256];
    h[threadIdx.x] = 0;
    __syncthreads();
    int base = blockIdx.x * CHUNK;
    int end = min(base + CHUNK, E);
    for (int i = base + threadIdx.x; i < end; i += 256)
        atomicAdd(&h[dst[i] >> B2SHIFT], 1);
    __syncthreads();
    H[blockIdx.x * 256 + threadIdx.x] = h[threadIdx.x];
}

// ---- col_scan_a: one block per column; exclusive scan over NR rows ----
__global__ __launch_bounds__(512) void col_scan_a(int* __restrict__ H,
                                                  int* __restrict__ ctot, int NR) {
    __shared__ int s[512];
    int b = blockIdx.x;   // column
    int t = threadIdx.x;  // row
    int v = (t < NR) ? H[t * 256 + b] : 0;
    s[t] = v;
    __syncthreads();
    for (int off = 1; off < 512; off <<= 1) {
        int a = (t >= off) ? s[t - off] : 0;
        __syncthreads();
        s[t] += a;
        __syncthreads();
    }
    if (t < NR) H[t * 256 + b] = s[t] - v;  // column-local exclusive
    if (t == 511) ctot[b] = s[511];         // column total
}

// ---- col_scan_b: scan column totals -> per-bucket bases ----
__global__ __launch_bounds__(256) void col_scan_b(const int* __restrict__ ctot,
                                                  int* __restrict__ cbase,
                                                  int* __restrict__ bbase,
                                                  int NB, int E) {
    __shared__ int s[256];
    int t = threadIdx.x;
    int v = ctot[t];
    s[t] = v;
    __syncthreads();
    for (int off = 1; off < 256; off <<= 1) {
        int a = (t >= off) ? s[t - off] : 0;
        __syncthreads();
        s[t] += a;
        __syncthreads();
    }
    int e = s[t] - v;
    cbase[t] = e;
    if (t < NB) bbase[t] = e;
    if (t == 0) bbase[NB] = E;
}

// ---- col_scan_c: H[r][b] += cbase[b] ----
__global__ __launch_bounds__(256) void col_scan_c(int* __restrict__ H,
                                                  const int* __restrict__ cbase) {
    H[blockIdx.x * 256 + threadIdx.x] += cbase[threadIdx.x];
}

// ---- pass B: place packed edges into private per-chunk runs ----
__global__ __launch_bounds__(256) void passB_place(const int* __restrict__ src,
                                                   const int* __restrict__ dst,
                                                   const int* __restrict__ H,
                                                   unsigned* __restrict__ bedges, int E) {
    __shared__ int cur[256];
    cur[threadIdx.x] = H[blockIdx.x * 256 + threadIdx.x];
    __syncthreads();
    int base = blockIdx.x * CHUNK;
    int end = min(base + CHUNK, E);
    for (int i = base + threadIdx.x; i < end; i += 256) {
        int d = dst[i];
        int p = atomicAdd(&cur[d >> B2SHIFT], 1);  // LDS atomic
        bedges[p] = ((unsigned)src[i] << B2SHIFT) | (unsigned)(d & 511);
    }
}

// ---- per-bucket histogram -> cnt[d] + dinv[d] (coalesced writes) ----
__global__ __launch_bounds__(256) void bucket_cnt(const int* __restrict__ bbase,
                                                  const unsigned* __restrict__ bedges,
                                                  int* __restrict__ cnt,
                                                  float* __restrict__ dinv, int n) {
    __shared__ int lh[512];
    lh[threadIdx.x] = 0;
    lh[threadIdx.x + 256] = 0;
    __syncthreads();
    int b = blockIdx.x;
    int beg = bbase[b], end = bbase[b + 1];
    for (int i = beg + threadIdx.x; i < end; i += 256)
        atomicAdd(&lh[bedges[i] & 511], 1);
    __syncthreads();
#pragma unroll
    for (int k = 0; k < 2; ++k) {
        int d = (b << B2SHIFT) + threadIdx.x + k * 256;
        if (d < n) {
            int c = lh[threadIdx.x + k * 256];
            cnt[d] = c;
            dinv[d] = rsqrtf((float)c + 1.0f);
        }
    }
}

// ---- 3-phase exclusive scan over cnt[n] -> row_ptr[n+1] ----
__global__ __launch_bounds__(256) void scan_phase1(const int* __restrict__ cnt,
                                                   int* __restrict__ excl,
                                                   int* __restrict__ bsum, int n) {
    __shared__ int s[256];
    int t = threadIdx.x;
    int i = blockIdx.x * 256 + t;
    int v = (i < n) ? cnt[i] : 0;
    s[t] = v;
    __syncthreads();
    for (int off = 1; off < 256; off <<= 1) {
        int add = (t >= off) ? s[t - off] : 0;
        __syncthreads();
        s[t] += add;
        __syncthreads();
    }
    if (i < n) excl[i] = s[t] - v;
    if (t == 255) bsum[blockIdx.x] = s[255];
}

__global__ __launch_bounds__(512) void scan_phase2(int* __restrict__ bsum, int nb) {
    __shared__ int s[512];
    int t = threadIdx.x;
    int v = (t < nb) ? bsum[t] : 0;
    s[t] = v;
    __syncthreads();
    for (int off = 1; off < 512; off <<= 1) {
        int add = (t >= off) ? s[t - off] : 0;
        __syncthreads();
        s[t] += add;
        __syncthreads();
    }
    if (t < nb) bsum[t] = s[t] - v;
}

__global__ __launch_bounds__(256) void scan_phase3(int* __restrict__ row_ptr,
                                                   const int* __restrict__ bsum,
                                                   int n, int E) {
    int i = blockIdx.x * 256 + threadIdx.x;
    if (i < n) row_ptr[i] += bsum[blockIdx.x];
    if (i == 0) row_ptr[n] = E;
}

// ---- scatter src into CSR via 512 LDS cursors (dense 32KB windows) ----
__global__ __launch_bounds__(256) void csr_fill(const int* __restrict__ bbase,
                                                const unsigned* __restrict__ bedges,
                                                const int* __restrict__ row_ptr,
                                                int* __restrict__ csr_src, int n) {
    __shared__ int cur[512];
#pragma unroll
    for (int k = 0; k < 2; ++k) {
        int d = (blockIdx.x << B2SHIFT) + threadIdx.x + k * 256;
        cur[threadIdx.x + k * 256] = (d < n) ? row_ptr[d] : 0;
    }
    __syncthreads();
    int beg = bbase[blockIdx.x], end = bbase[blockIdx.x + 1];
    for (int i = beg + threadIdx.x; i < end; i += 256) {
        unsigned v = bedges[i];
        int p = atomicAdd(&cur[v & 511], 1);  // LDS atomic
        csr_src[p] = (int)(v >> B2SHIFT);
    }
}

// ---- GEMM: out[n,FO] = dinv[row] * (preop(A[n,64]) * W[64,FO]) ----
template <int FO, bool RELU_BIAS>
__global__ __launch_bounds__(256) void gemm_rows(const float* __restrict__ A,
                                                 const float* __restrict__ W,
                                                 const float* __restrict__ bias,
                                                 const float* __restrict__ dinv,
                                                 float* __restrict__ out, int n) {
    constexpr int K = 64;
    constexpr int CPT = FO / 4;
    __shared__ float As[64][K + 4];
    __shared__ float Ws[K][FO];

    const int t = threadIdx.x;
    const int r0 = blockIdx.x * 64;

    constexpr int W4 = K * FO / 4;
    for (int i = t; i < W4; i += 256) {
        int k = i / (FO / 4);
        int c4 = (i % (FO / 4)) * 4;
        *(float4*)&Ws[k][c4] = *(const float4*)&W[k * FO + c4];
    }
    for (int i = t; i < 1024; i += 256) {
        int row = i / 16;
        int c4 = (i % 16) * 4;
        int g = r0 + row;
        float4 v = make_float4(0.f, 0.f, 0.f, 0.f);
        if (g < n) {
            v = *(const float4*)&A[(size_t)g * K + c4];
            if (RELU_BIAS) {
                v.x = fmaxf(v.x + bias[c4 + 0], 0.f);
                v.y = fmaxf(v.y + bias[c4 + 1], 0.f);
                v.z = fmaxf(v.z + bias[c4 + 2], 0.f);
                v.w = fmaxf(v.w + bias[c4 + 3], 0.f);
            }
        }
        *(float4*)&As[row][c4] = v;
    }
    __syncthreads();

    const int row = t >> 2;
    const int c0 = (t & 3) * CPT;
    float acc[CPT];
#pragma unroll
    for (int j = 0; j < CPT; ++j) acc[j] = 0.f;

#pragma unroll
    for (int k = 0; k < K; ++k) {
        float xv = As[row][k];
#pragma unroll
        for (int j = 0; j < CPT; ++j) acc[j] = fmaf(xv, Ws[k][c0 + j], acc[j]);
    }

    int g = r0 + row;
    if (g < n) {
        float sc = dinv[g];
#pragma unroll
        for (int j4 = 0; j4 < CPT; j4 += 4) {
            float4 v = make_float4(acc[j4] * sc, acc[j4 + 1] * sc,
                                   acc[j4 + 2] * sc, acc[j4 + 3] * sc);
            *(float4*)&out[(size_t)g * FO + c0 + j4] = v;
        }
    }
}

// ---- pull aggregation: out[d,f] = dinv[d]*(sum_{s in N(d)} xs[s,f] + xs[d,f]) (+bias) ----
template <int F, bool ADD_BIAS>
__global__ __launch_bounds__(256) void aggregate(const int* __restrict__ row_ptr,
                                                 const int* __restrict__ csr_src,
                                                 const float* __restrict__ dinv,
                                                 const float* __restrict__ xs,
                                                 const float* __restrict__ bias,
                                                 float* __restrict__ out, int n) {
    constexpr int NPB = 256 / F;
    constexpr int SH = (F == 64) ? 6 : 5;
    int d = blockIdx.x * NPB + (threadIdx.x >> SH);
    int f = threadIdx.x & (F - 1);
    if (d >= n) return;

    int beg = row_ptr[d];
    int end = row_ptr[d + 1];
    float acc = xs[(size_t)d * F + f];
    int j = beg;
    for (; j + 4 <= end; j += 4) {
        int s0 = csr_src[j + 0];
        int s1 = csr_src[j + 1];
        int s2 = csr_src[j + 2];
        int s3 = csr_src[j + 3];
        float v0 = xs[(size_t)s0 * F + f];
        float v1 = xs[(size_t)s1 * F + f];
        float v2 = xs[(size_t)s2 * F + f];
        float v3 = xs[(size_t)s3 * F + f];
        acc += (v0 + v1) + (v2 + v3);
    }
    for (; j < end; ++j) acc += xs[(size_t)csr_src[j] * F + f];

    float r = dinv[d] * acc;
    if (ADD_BIAS) r += bias[f];
    out[(size_t)d * F + f] = r;
}

extern "C" void kernel_launch(void* const* d_in, const int* in_sizes, int n_in,
                              void* d_out, int out_size, void* d_ws, size_t ws_size,
                              hipStream_t stream) {
    const float* x  = (const float*)d_in[0];   // [n, 64]
    const int*   ei = (const int*)d_in[1];     // [2, E]
    const float* W1 = (const float*)d_in[2];   // [64, 64]
    const float* b1 = (const float*)d_in[3];   // [64]
    const float* W2 = (const float*)d_in[4];   // [64, 32]
    const float* b2 = (const float*)d_in[5];   // [32]
    float* out = (float*)d_out;                // [n, 32]

    const int n = in_sizes[0] / N_FEAT_IN;     // 100000
    const int E = in_sizes[1] / 2;             // 1600000
    const int* srcI = ei;
    const int* dstI = ei + E;

    const int NB     = (n + 511) >> B2SHIFT;   // 196 coarse buckets
    const int NR     = (E + CHUNK - 1) / CHUNK;// 391 chunks
    const int NBLK   = (n + 255) / 256;        // row_ptr scan blocks (391)

    // workspace layout (256B aligned)
    char* ws = (char*)d_ws;
    size_t off = 0;
    auto alloc = [&](size_t bytes) {
        void* p = ws + off;
        off += (bytes + 255) & ~(size_t)255;
        return p;
    };
    int*      cnt     = (int*)alloc((size_t)n * 4);
    float*    dinv    = (float*)alloc((size_t)n * 4);
    int*      row_ptr = (int*)alloc((size_t)(n + 1) * 4);
    int*      bsum    = (int*)alloc((size_t)512 * 4);
    int*      bbase   = (int*)alloc((size_t)(NB + 1) * 4);
    int*      ctot    = (int*)alloc((size_t)256 * 4);
    int*      cbase   = (int*)alloc((size_t)256 * 4);
    int*      H       = (int*)alloc((size_t)NR * 256 * 4);   // ~400KB
    unsigned* bedges  = (unsigned*)alloc((size_t)E * 4);
    int*      csr_src = (int*)alloc((size_t)E * 4);
    float*    xs      = (float*)alloc((size_t)n * 64 * 4);
    float*    agg1    = (float*)alloc((size_t)n * 64 * 4);

    // 1) atomic-free bucket sort by dst>>9
    passA_hist<<<NR, 256, 0, stream>>>(dstI, H, E);
    col_scan_a<<<256, 512, 0, stream>>>(H, ctot, NR);
    col_scan_b<<<1, 256, 0, stream>>>(ctot, cbase, bbase, NB, E);
    col_scan_c<<<NR, 256, 0, stream>>>(H, cbase);
    passB_place<<<NR, 256, 0, stream>>>(srcI, dstI, H, bedges, E);

    // 2) per-node counts + dinv, row_ptr scan, CSR scatter
    bucket_cnt<<<NB, 256, 0, stream>>>(bbase, bedges, cnt, dinv, n);
    scan_phase1<<<NBLK, 256, 0, stream>>>(cnt, row_ptr, bsum, n);
    scan_phase2<<<1, 512, 0, stream>>>(bsum, NBLK);
    scan_phase3<<<NBLK, 256, 0, stream>>>(row_ptr, bsum, n, E);
    csr_fill<<<NB, 256, 0, stream>>>(bbase, bedges, row_ptr, csr_src, n);

    // 3) layer 1: xs = dinv .* (X W1); agg1 = dinv .* (gather-sum + self)
    gemm_rows<64, false><<<(n + 63) / 64, 256, 0, stream>>>(x, W1, nullptr, dinv, xs, n);
    aggregate<64, false><<<(n + 3) / 4, 256, 0, stream>>>(row_ptr, csr_src, dinv, xs, nullptr, agg1, n);

    // 4) layer 2: xs2 = dinv .* (relu(agg1+b1) W2); out = dinv .* (gather-sum + self) + b2
    gemm_rows<32, true><<<(n + 63) / 64, 256, 0, stream>>>(agg1, W2, b1, dinv, xs, n);
    aggregate<32, true><<<(n + 7) / 8, 256, 0, stream>>>(row_ptr, csr_src, dinv, xs, b2, out, n);
}

// Round 6
// 256.231 us; speedup vs baseline: 2.8592x; 1.1469x over previous
//
#include <hip/hip_runtime.h>
#include <hip/hip_bf16.h>
#include <hip/hip_fp16.h>

// GCN 2-layer: out = Ahat * relu(Ahat*(X W1)+b1) * W2 + b2
// Round 6:
//  - fp16 gather tables xs/xs2 (halves the E-way random-gather traffic);
//    accumulation + agg1 + out stay fp32.
//  - row_ptr[d] = bbase[d>>9] + bucket-local exclusive scan -> cnt array and
//    the 3 n-wide scan kernels deleted (fused into bucket_rowptr).
//  - col_scan_c fused into passB (cursor seed adds cbase).
//  - aggregate unrolled x8.

#define N_FEAT_IN 64
#define B2SHIFT 9        // 512 dst nodes per coarse bucket
#define CHUNK 4096       // edges per block in pass A/B

struct alignas(8) half4 { __half2 lo, hi; };

// ---- pass A: per-chunk bucket histogram (LDS, no global atomics) ----
__global__ __launch_bounds__(256) void passA_hist(const int* __restrict__ dst,
                                                  int* __restrict__ H, int E) {
    __shared__ int h[256];
    h[threadIdx.x] = 0;
    __syncthreads();
    int base = blockIdx.x * CHUNK;
    int end = min(base + CHUNK, E);
    for (int i = base + threadIdx.x; i < end; i += 256)
        atomicAdd(&h[dst[i] >> B2SHIFT], 1);
    __syncthreads();
    H[blockIdx.x * 256 + threadIdx.x] = h[threadIdx.x];
}

// ---- col_scan_a: one block per column; exclusive scan over NR rows ----
__global__ __launch_bounds__(512) void col_scan_a(int* __restrict__ H,
                                                  int* __restrict__ ctot, int NR) {
    __shared__ int s[512];
    int b = blockIdx.x;
    int t = threadIdx.x;
    int v = (t < NR) ? H[t * 256 + b] : 0;
    s[t] = v;
    __syncthreads();
    for (int off = 1; off < 512; off <<= 1) {
        int a = (t >= off) ? s[t - off] : 0;
        __syncthreads();
        s[t] += a;
        __syncthreads();
    }
    if (t < NR) H[t * 256 + b] = s[t] - v;
    if (t == 511) ctot[b] = s[511];
}

// ---- col_scan_b: scan column totals -> per-bucket bases; row_ptr[n]=E ----
__global__ __launch_bounds__(256) void col_scan_b(const int* __restrict__ ctot,
                                                  int* __restrict__ cbase,
                                                  int* __restrict__ bbase,
                                                  int* __restrict__ row_ptr,
                                                  int NB, int n, int E) {
    __shared__ int s[256];
    int t = threadIdx.x;
    int v = ctot[t];
    s[t] = v;
    __syncthreads();
    for (int off = 1; off < 256; off <<= 1) {
        int a = (t >= off) ? s[t - off] : 0;
        __syncthreads();
        s[t] += a;
        __syncthreads();
    }
    int e = s[t] - v;
    cbase[t] = e;
    if (t < NB) bbase[t] = e;
    if (t == 0) { bbase[NB] = E; row_ptr[n] = E; }
}

// ---- pass B: place packed edges into private per-chunk runs (cbase fused) ----
__global__ __launch_bounds__(256) void passB_place(const int* __restrict__ src,
                                                   const int* __restrict__ dst,
                                                   const int* __restrict__ H,
                                                   const int* __restrict__ cbase,
                                                   unsigned* __restrict__ bedges, int E) {
    __shared__ int cur[256];
    cur[threadIdx.x] = H[blockIdx.x * 256 + threadIdx.x] + cbase[threadIdx.x];
    __syncthreads();
    int base = blockIdx.x * CHUNK;
    int end = min(base + CHUNK, E);
    for (int i = base + threadIdx.x; i < end; i += 256) {
        int d = dst[i];
        int p = atomicAdd(&cur[d >> B2SHIFT], 1);  // LDS atomic
        bedges[p] = ((unsigned)src[i] << B2SHIFT) | (unsigned)(d & 511);
    }
}

// ---- per-bucket hist + local scan -> row_ptr[d], dinv[d] (coalesced) ----
__global__ __launch_bounds__(256) void bucket_rowptr(const int* __restrict__ bbase,
                                                     const unsigned* __restrict__ bedges,
                                                     int* __restrict__ row_ptr,
                                                     float* __restrict__ dinv, int n) {
    __shared__ int lh[512];
    int t = threadIdx.x;
    lh[t] = 0;
    lh[t + 256] = 0;
    __syncthreads();
    int b = blockIdx.x;
    int beg = bbase[b], end = bbase[b + 1];
    for (int i = beg + t; i < end; i += 256)
        atomicAdd(&lh[bedges[i] & 511], 1);
    __syncthreads();
    int c0 = lh[t], c1 = lh[t + 256];
    // 512-wide Hillis-Steele inclusive scan, 2 elems/thread
    for (int off = 1; off < 512; off <<= 1) {
        int a0 = (t >= off) ? lh[t - off] : 0;
        int a1 = (t + 256 >= off) ? lh[t + 256 - off] : 0;
        __syncthreads();
        lh[t] += a0;
        lh[t + 256] += a1;
        __syncthreads();
    }
    int base = bbase[b];
#pragma unroll
    for (int k = 0; k < 2; ++k) {
        int local = t + k * 256;
        int d = (b << B2SHIFT) + local;
        if (d < n) {
            int c = (k == 0) ? c0 : c1;
            row_ptr[d] = base + lh[local] - c;     // exclusive
            dinv[d] = rsqrtf((float)c + 1.0f);
        }
    }
}

// ---- scatter src into CSR via 512 LDS cursors (dense 32KB windows) ----
__global__ __launch_bounds__(256) void csr_fill(const int* __restrict__ bbase,
                                                const unsigned* __restrict__ bedges,
                                                const int* __restrict__ row_ptr,
                                                int* __restrict__ csr_src, int n) {
    __shared__ int cur[512];
#pragma unroll
    for (int k = 0; k < 2; ++k) {
        int d = (blockIdx.x << B2SHIFT) + threadIdx.x + k * 256;
        cur[threadIdx.x + k * 256] = (d < n) ? row_ptr[d] : 0;
    }
    __syncthreads();
    int beg = bbase[blockIdx.x], end = bbase[blockIdx.x + 1];
    for (int i = beg + threadIdx.x; i < end; i += 256) {
        unsigned v = bedges[i];
        int p = atomicAdd(&cur[v & 511], 1);  // LDS atomic
        csr_src[p] = (int)(v >> B2SHIFT);
    }
}

// ---- GEMM: outh[n,FO] = half( dinv[row] * (preop(A[n,64]) * W[64,FO]) ) ----
template <int FO, bool RELU_BIAS>
__global__ __launch_bounds__(256) void gemm_rows(const float* __restrict__ A,
                                                 const float* __restrict__ W,
                                                 const float* __restrict__ bias,
                                                 const float* __restrict__ dinv,
                                                 __half* __restrict__ outh, int n) {
    constexpr int K = 64;
    constexpr int CPT = FO / 4;
    __shared__ float As[64][K + 4];
    __shared__ float Ws[K][FO];

    const int t = threadIdx.x;
    const int r0 = blockIdx.x * 64;

    constexpr int W4 = K * FO / 4;
    for (int i = t; i < W4; i += 256) {
        int k = i / (FO / 4);
        int c4 = (i % (FO / 4)) * 4;
        *(float4*)&Ws[k][c4] = *(const float4*)&W[k * FO + c4];
    }
    for (int i = t; i < 1024; i += 256) {
        int row = i / 16;
        int c4 = (i % 16) * 4;
        int g = r0 + row;
        float4 v = make_float4(0.f, 0.f, 0.f, 0.f);
        if (g < n) {
            v = *(const float4*)&A[(size_t)g * K + c4];
            if (RELU_BIAS) {
                v.x = fmaxf(v.x + bias[c4 + 0], 0.f);
                v.y = fmaxf(v.y + bias[c4 + 1], 0.f);
                v.z = fmaxf(v.z + bias[c4 + 2], 0.f);
                v.w = fmaxf(v.w + bias[c4 + 3], 0.f);
            }
        }
        *(float4*)&As[row][c4] = v;
    }
    __syncthreads();

    const int row = t >> 2;
    const int c0 = (t & 3) * CPT;
    float acc[CPT];
#pragma unroll
    for (int j = 0; j < CPT; ++j) acc[j] = 0.f;

#pragma unroll
    for (int k = 0; k < K; ++k) {
        float xv = As[row][k];
#pragma unroll
        for (int j = 0; j < CPT; ++j) acc[j] = fmaf(xv, Ws[k][c0 + j], acc[j]);
    }

    int g = r0 + row;
    if (g < n) {
        float sc = dinv[g];
#pragma unroll
        for (int j4 = 0; j4 < CPT; j4 += 4) {
            half4 h;
            h.lo = __floats2half2_rn(acc[j4] * sc, acc[j4 + 1] * sc);
            h.hi = __floats2half2_rn(acc[j4 + 2] * sc, acc[j4 + 3] * sc);
            *(half4*)&outh[(size_t)g * FO + c0 + j4] = h;
        }
    }
}

// ---- pull aggregation: out[d,f] = dinv[d]*(sum_{s in N(d)} xs[s,f] + xs[d,f]) (+bias) ----
template <int F, bool ADD_BIAS>
__global__ __launch_bounds__(256) void aggregate(const int* __restrict__ row_ptr,
                                                 const int* __restrict__ csr_src,
                                                 const float* __restrict__ dinv,
                                                 const __half* __restrict__ xs,
                                                 const float* __restrict__ bias,
                                                 float* __restrict__ out, int n) {
    constexpr int NPB = 256 / F;
    constexpr int SH = (F == 64) ? 6 : 5;
    int d = blockIdx.x * NPB + (threadIdx.x >> SH);
    int f = threadIdx.x & (F - 1);
    if (d >= n) return;

    int beg = row_ptr[d];
    int end = row_ptr[d + 1];
    float acc = __half2float(xs[(size_t)d * F + f]);  // self-loop term
    int j = beg;
    for (; j + 8 <= end; j += 8) {
        int s0 = csr_src[j + 0], s1 = csr_src[j + 1];
        int s2 = csr_src[j + 2], s3 = csr_src[j + 3];
        int s4 = csr_src[j + 4], s5 = csr_src[j + 5];
        int s6 = csr_src[j + 6], s7 = csr_src[j + 7];
        float v0 = __half2float(xs[(size_t)s0 * F + f]);
        float v1 = __half2float(xs[(size_t)s1 * F + f]);
        float v2 = __half2float(xs[(size_t)s2 * F + f]);
        float v3 = __half2float(xs[(size_t)s3 * F + f]);
        float v4 = __half2float(xs[(size_t)s4 * F + f]);
        float v5 = __half2float(xs[(size_t)s5 * F + f]);
        float v6 = __half2float(xs[(size_t)s6 * F + f]);
        float v7 = __half2float(xs[(size_t)s7 * F + f]);
        acc += ((v0 + v1) + (v2 + v3)) + ((v4 + v5) + (v6 + v7));
    }
    for (; j + 4 <= end; j += 4) {
        int s0 = csr_src[j + 0], s1 = csr_src[j + 1];
        int s2 = csr_src[j + 2], s3 = csr_src[j + 3];
        float v0 = __half2float(xs[(size_t)s0 * F + f]);
        float v1 = __half2float(xs[(size_t)s1 * F + f]);
        float v2 = __half2float(xs[(size_t)s2 * F + f]);
        float v3 = __half2float(xs[(size_t)s3 * F + f]);
        acc += (v0 + v1) + (v2 + v3);
    }
    for (; j < end; ++j) acc += __half2float(xs[(size_t)csr_src[j] * F + f]);

    float r = dinv[d] * acc;
    if (ADD_BIAS) r += bias[f];
    out[(size_t)d * F + f] = r;
}

extern "C" void kernel_launch(void* const* d_in, const int* in_sizes, int n_in,
                              void* d_out, int out_size, void* d_ws, size_t ws_size,
                              hipStream_t stream) {
    const float* x  = (const float*)d_in[0];   // [n, 64]
    const int*   ei = (const int*)d_in[1];     // [2, E]
    const float* W1 = (const float*)d_in[2];   // [64, 64]
    const float* b1 = (const float*)d_in[3];   // [64]
    const float* W2 = (const float*)d_in[4];   // [64, 32]
    const float* b2 = (const float*)d_in[5];   // [32]
    float* out = (float*)d_out;                // [n, 32]

    const int n = in_sizes[0] / N_FEAT_IN;     // 100000
    const int E = in_sizes[1] / 2;             // 1600000
    const int* srcI = ei;
    const int* dstI = ei + E;

    const int NB = (n + 511) >> B2SHIFT;       // 196 coarse buckets
    const int NR = (E + CHUNK - 1) / CHUNK;    // 391 chunks

    // workspace layout (256B aligned)
    char* ws = (char*)d_ws;
    size_t off = 0;
    auto alloc = [&](size_t bytes) {
        void* p = ws + off;
        off += (bytes + 255) & ~(size_t)255;
        return p;
    };
    float*    dinv    = (float*)alloc((size_t)n * 4);
    int*      row_ptr = (int*)alloc((size_t)(n + 1) * 4);
    int*      bbase   = (int*)alloc((size_t)(NB + 1) * 4);
    int*      ctot    = (int*)alloc((size_t)256 * 4);
    int*      cbase   = (int*)alloc((size_t)256 * 4);
    int*      H       = (int*)alloc((size_t)NR * 256 * 4);   // ~400KB
    unsigned* bedges  = (unsigned*)alloc((size_t)E * 4);
    int*      csr_src = (int*)alloc((size_t)E * 4);
    __half*   xs      = (__half*)alloc((size_t)n * 64 * 2);  // fp16 gather table
    float*    agg1    = (float*)alloc((size_t)n * 64 * 4);

    // 1) atomic-free bucket sort by dst>>9
    passA_hist<<<NR, 256, 0, stream>>>(dstI, H, E);
    col_scan_a<<<256, 512, 0, stream>>>(H, ctot, NR);
    col_scan_b<<<1, 256, 0, stream>>>(ctot, cbase, bbase, row_ptr, NB, n, E);
    passB_place<<<NR, 256, 0, stream>>>(srcI, dstI, H, cbase, bedges, E);

    // 2) row_ptr + dinv (bucket-local scan), CSR scatter
    bucket_rowptr<<<NB, 256, 0, stream>>>(bbase, bedges, row_ptr, dinv, n);
    csr_fill<<<NB, 256, 0, stream>>>(bbase, bedges, row_ptr, csr_src, n);

    // 3) layer 1: xs = half(dinv .* (X W1)); agg1 = dinv .* (gather-sum + self)
    gemm_rows<64, false><<<(n + 63) / 64, 256, 0, stream>>>(x, W1, nullptr, dinv, xs, n);
    aggregate<64, false><<<(n + 3) / 4, 256, 0, stream>>>(row_ptr, csr_src, dinv, xs, nullptr, agg1, n);

    // 4) layer 2: xs2 = half(dinv .* (relu(agg1+b1) W2)); out = dinv .* (...) + b2
    gemm_rows<32, true><<<(n + 63) / 64, 256, 0, stream>>>(agg1, W2, b1, dinv, xs, n);
    aggregate<32, true><<<(n + 7) / 8, 256, 0, stream>>>(row_ptr, csr_src, dinv, xs, b2, out, n);
}